// Round 7
// baseline (265.348 us; speedup 1.0000x reference)
//
#include <hip/hip_runtime.h>
#include <math.h>

#define KK 5
#define WPOUT 28
#define PPI 784          // patches per image (28*28)
#define NCH 64
#define NPATCH 25088     // 32*784
#define THREADS 128
#define TP 4             // patches per thread; 128*4=512 patches/block; 49 blocks exact

typedef float f32x32 __attribute__((ext_vector_type(32)));
typedef float f32x16 __attribute__((ext_vector_type(16)));

struct F4 { float2 ab, cd; };   // 4 patch lanes: (A,B) and (C,D) pairs

// Evaluate one 4-input LUT node for 4 patches.
// lr: block-uniform LDS row, [0..7]=sigmoid(lut[2k]) (e), [8..15]=sigmoid(lut[2k+1])-e (d).
// s0 = most significant address bit (contracted last), s3 least significant.
// Written pairwise on float2 so SLP can form v_pk_fma_f32; e/d loaded once, reused x4.
__device__ __forceinline__ F4 node4(const float* __restrict__ lr,
                                    F4 s0, F4 s1, F4 s2, F4 s3)
{
    float e[8], dd[8];
#pragma unroll
    for (int k = 0; k < 8; ++k) { e[k] = lr[k]; dd[k] = lr[k + 8]; }

    float2 vab[8], vcd[8];
#pragma unroll
    for (int k = 0; k < 8; ++k) {
        vab[k] = make_float2(fmaf(s3.ab.x, dd[k], e[k]), fmaf(s3.ab.y, dd[k], e[k]));
        vcd[k] = make_float2(fmaf(s3.cd.x, dd[k], e[k]), fmaf(s3.cd.y, dd[k], e[k]));
    }
    float2 wab[4], wcd[4];
#pragma unroll
    for (int k = 0; k < 4; ++k) {
        wab[k].x = fmaf(s2.ab.x, vab[2 * k + 1].x - vab[2 * k].x, vab[2 * k].x);
        wab[k].y = fmaf(s2.ab.y, vab[2 * k + 1].y - vab[2 * k].y, vab[2 * k].y);
        wcd[k].x = fmaf(s2.cd.x, vcd[2 * k + 1].x - vcd[2 * k].x, vcd[2 * k].x);
        wcd[k].y = fmaf(s2.cd.y, vcd[2 * k + 1].y - vcd[2 * k].y, vcd[2 * k].y);
    }
    float u0abx = fmaf(s1.ab.x, wab[1].x - wab[0].x, wab[0].x);
    float u1abx = fmaf(s1.ab.x, wab[3].x - wab[2].x, wab[2].x);
    float u0aby = fmaf(s1.ab.y, wab[1].y - wab[0].y, wab[0].y);
    float u1aby = fmaf(s1.ab.y, wab[3].y - wab[2].y, wab[2].y);
    float u0cdx = fmaf(s1.cd.x, wcd[1].x - wcd[0].x, wcd[0].x);
    float u1cdx = fmaf(s1.cd.x, wcd[3].x - wcd[2].x, wcd[2].x);
    float u0cdy = fmaf(s1.cd.y, wcd[1].y - wcd[0].y, wcd[0].y);
    float u1cdy = fmaf(s1.cd.y, wcd[3].y - wcd[2].y, wcd[2].y);

    F4 r;
    r.ab.x = fmaf(s0.ab.x, u1abx - u0abx, u0abx);
    r.ab.y = fmaf(s0.ab.y, u1aby - u0aby, u0aby);
    r.cd.x = fmaf(s0.cd.x, u1cdx - u0cdx, u0cdx);
    r.cd.y = fmaf(s0.cd.y, u1cdy - u0cdy, u0cdy);
    return r;
}

__global__ __launch_bounds__(THREADS, 2)
void dwn_conv_lut_kernel(const float* __restrict__ x,     // [32,1,32,32]
                         const float* __restrict__ lut0,  // [64,16,16]
                         const float* __restrict__ lut1,  // [64,4,16]
                         const float* __restrict__ lut2,  // [64,1,16]
                         const int*   __restrict__ idx0,  // [64,16,4]
                         const int*   __restrict__ idx1,  // [64,4,4]
                         const int*   __restrict__ idx2,  // [64,1,4]
                         float*       __restrict__ out)   // [32,64,28,28]
{
    __shared__ float l0[16][16];
    __shared__ float l1[4][16];
    __shared__ float l2[16];

    const int tid = threadIdx.x;
    const int c   = blockIdx.y;

    // ---- stage sigmoided LUTs (e,d layout): 168 pairs over 128 threads ----
    for (int t = tid; t < 168; t += THREADS) {
        const float* src;
        float* dst;
        int k = t & 7;
        if (t < 128) {                       // lut0: 16 nodes * 8 pairs
            int node = t >> 3;
            src = lut0 + (c * 16 + node) * 16;
            dst = &l0[node][0];
        } else if (t < 160) {                // lut1: 4 nodes * 8 pairs
            int node = (t - 128) >> 3;
            src = lut1 + (c * 4 + node) * 16;
            dst = &l1[node][0];
        } else {                             // lut2
            src = lut2 + c * 16;
            dst = l2;
        }
        float a = src[2 * k], b = src[2 * k + 1];
        float ea = 1.0f / (1.0f + __expf(-a));
        float eb = 1.0f / (1.0f + __expf(-b));
        dst[k]     = ea;
        dst[k + 8] = eb - ea;
    }

    // ---- 4 patches per thread ----
    const int p0 = blockIdx.x * (TP * THREADS) + tid;
    const int pP[TP] = { p0, p0 + THREADS, p0 + 2 * THREADS, p0 + 3 * THREADS };

    int bP[TP], qP[TP];
    const float* xP[TP];
#pragma unroll
    for (int t = 0; t < TP; ++t) {
        bP[t] = pP[t] / PPI;
        qP[t] = pP[t] - bP[t] * PPI;
        const int i = qP[t] / WPOUT;
        const int j = qP[t] - i * WPOUT;
        xP[t] = x + bP[t] * 1024 + i * 32 + j;
    }

    f32x32 pvA, pvB, pvC, pvD;
#pragma unroll
    for (int di = 0; di < KK; ++di) {
#pragma unroll
        for (int dj = 0; dj < KK; ++dj) {
            const int o = di * 5 + dj, go = di * 32 + dj;
            pvA[o] = xP[0][go];
            pvB[o] = xP[1][go];
            pvC[o] = xP[2][go];
            pvD[o] = xP[3][go];
        }
    }

    __syncthreads();   // LUTs ready

    // ---- layer 0: 16 nodes; uniform-index movrel gathers (shared m0 across 4 vectors) ----
    const int* id0 = idx0 + c * 64;
    f32x16 hA, hB, hC, hD;
#pragma unroll
    for (int m = 0; m < 16; ++m) {
        const int i0 = __builtin_amdgcn_readfirstlane(id0[m * 4 + 0]);
        const int i1 = __builtin_amdgcn_readfirstlane(id0[m * 4 + 1]);
        const int i2 = __builtin_amdgcn_readfirstlane(id0[m * 4 + 2]);
        const int i3 = __builtin_amdgcn_readfirstlane(id0[m * 4 + 3]);
        F4 s0 = { make_float2(pvA[i0], pvB[i0]), make_float2(pvC[i0], pvD[i0]) };
        F4 s1 = { make_float2(pvA[i1], pvB[i1]), make_float2(pvC[i1], pvD[i1]) };
        F4 s2 = { make_float2(pvA[i2], pvB[i2]), make_float2(pvC[i2], pvD[i2]) };
        F4 s3 = { make_float2(pvA[i3], pvB[i3]), make_float2(pvC[i3], pvD[i3]) };
        F4 r = node4(&l0[m][0], s0, s1, s2, s3);
        hA[m] = r.ab.x; hB[m] = r.ab.y; hC[m] = r.cd.x; hD[m] = r.cd.y;
    }

    // ---- layer 1: 4 nodes; uniform-index movrel gathers from h ----
    const int* id1 = idx1 + c * 16;
    F4 h1[4];
#pragma unroll
    for (int m = 0; m < 4; ++m) {
        const int i0 = __builtin_amdgcn_readfirstlane(id1[m * 4 + 0]);
        const int i1 = __builtin_amdgcn_readfirstlane(id1[m * 4 + 1]);
        const int i2 = __builtin_amdgcn_readfirstlane(id1[m * 4 + 2]);
        const int i3 = __builtin_amdgcn_readfirstlane(id1[m * 4 + 3]);
        F4 s0 = { make_float2(hA[i0], hB[i0]), make_float2(hC[i0], hD[i0]) };
        F4 s1 = { make_float2(hA[i1], hB[i1]), make_float2(hC[i1], hD[i1]) };
        F4 s2 = { make_float2(hA[i2], hB[i2]), make_float2(hC[i2], hD[i2]) };
        F4 s3 = { make_float2(hA[i3], hB[i3]), make_float2(hC[i3], hD[i3]) };
        h1[m] = node4(&l1[m][0], s0, s1, s2, s3);
    }

    // ---- layer 2: 1 node; 4-way uniform select from h1 (constant indices) ----
    const int* id2 = idx2 + c * 4;
    F4 s[4];
#pragma unroll
    for (int jj = 0; jj < 4; ++jj) {
        const int ii = __builtin_amdgcn_readfirstlane(id2[jj]);
        s[jj].ab.x = (ii == 0) ? h1[0].ab.x : (ii == 1) ? h1[1].ab.x : (ii == 2) ? h1[2].ab.x : h1[3].ab.x;
        s[jj].ab.y = (ii == 0) ? h1[0].ab.y : (ii == 1) ? h1[1].ab.y : (ii == 2) ? h1[2].ab.y : h1[3].ab.y;
        s[jj].cd.x = (ii == 0) ? h1[0].cd.x : (ii == 1) ? h1[1].cd.x : (ii == 2) ? h1[2].cd.x : h1[3].cd.x;
        s[jj].cd.y = (ii == 0) ? h1[0].cd.y : (ii == 1) ? h1[1].cd.y : (ii == 2) ? h1[2].cd.y : h1[3].cd.y;
    }
    const F4 r = node4(l2, s[0], s[1], s[2], s[3]);

    out[(bP[0] * NCH + c) * PPI + qP[0]] = r.ab.x;
    out[(bP[1] * NCH + c) * PPI + qP[1]] = r.ab.y;
    out[(bP[2] * NCH + c) * PPI + qP[2]] = r.cd.x;
    out[(bP[3] * NCH + c) * PPI + qP[3]] = r.cd.y;
}

extern "C" void kernel_launch(void* const* d_in, const int* in_sizes, int n_in,
                              void* d_out, int out_size, void* d_ws, size_t ws_size,
                              hipStream_t stream) {
    const float* x    = (const float*)d_in[0];
    const float* lut0 = (const float*)d_in[1];
    const float* lut1 = (const float*)d_in[2];
    const float* lut2 = (const float*)d_in[3];
    const int*   idx0 = (const int*)d_in[4];
    const int*   idx1 = (const int*)d_in[5];
    const int*   idx2 = (const int*)d_in[6];
    float* out = (float*)d_out;

    dim3 grid(NPATCH / (TP * THREADS), NCH);   // 49 x 64
    dim3 block(THREADS);
    dwn_conv_lut_kernel<<<grid, block, 0, stream>>>(x, lut0, lut1, lut2,
                                                    idx0, idx1, idx2, out);
}

// Round 8
// 27.725 us; speedup vs baseline: 9.5706x; 9.5706x over previous
//
#include <hip/hip_runtime.h>
#include <math.h>

#define KK 5
#define WPOUT 28
#define PPI 784          // patches per image (28*28)
#define NCH 64
#define NPATCH 25088     // 32*784
#define THREADS 256
#define TP 2             // patches per thread; 256*2=512 patches/block; 49 blocks exact

typedef float f32x32 __attribute__((ext_vector_type(32)));
typedef float f32x16 __attribute__((ext_vector_type(16)));
typedef float v2f    __attribute__((ext_vector_type(2)));   // (patchA, patchB)

// Evaluate one 4-input LUT node for 2 patches packed in v2f.
// lr: block-uniform LDS row: [0..7] = sigmoid(lut[2k]) (e), [8..15] = sigmoid(lut[2k+1]) - e (d).
// s0 = most significant address bit (contracted last), s3 least significant.
// All ops are v2f (<2 x float>) -> backend emits v_pk_fma_f32 / v_pk_add_f32;
// the LDS scalars splat to both halves (op_sel), no duplication cost.
__device__ __forceinline__ v2f node2(const float* __restrict__ lr,
                                     v2f s0, v2f s1, v2f s2, v2f s3)
{
    v2f v[8];
#pragma unroll
    for (int k = 0; k < 8; ++k)
        v[k] = s3 * lr[k + 8] + lr[k];          // pk_fma, scalar splat operands
    v2f w[4];
#pragma unroll
    for (int k = 0; k < 4; ++k)
        w[k] = s2 * (v[2 * k + 1] - v[2 * k]) + v[2 * k];
    v2f u0 = s1 * (w[1] - w[0]) + w[0];
    v2f u1 = s1 * (w[3] - w[2]) + w[2];
    return s0 * (u1 - u0) + u0;
}

__global__ __launch_bounds__(THREADS)
void dwn_conv_lut_kernel(const float* __restrict__ x,     // [32,1,32,32]
                         const float* __restrict__ lut0,  // [64,16,16]
                         const float* __restrict__ lut1,  // [64,4,16]
                         const float* __restrict__ lut2,  // [64,1,16]
                         const int*   __restrict__ idx0,  // [64,16,4]
                         const int*   __restrict__ idx1,  // [64,4,4]
                         const int*   __restrict__ idx2,  // [64,1,4]
                         float*       __restrict__ out)   // [32,64,28,28]
{
    __shared__ float l0[16][16];           // per node: e[8], d[8]
    __shared__ float l1[4][16];
    __shared__ float l2[16];

    const int tid = threadIdx.x;
    const int c   = blockIdx.y;

    // ---- stage sigmoided LUTs in (e,d) layout: 168 pairs, one per thread ----
    if (tid < 168) {
        const float* src;
        float* dst;
        int k;
        if (tid < 128) {                     // lut0: 16 nodes * 8 pairs
            int node = tid >> 3; k = tid & 7;
            src = lut0 + (c * 16 + node) * 16;
            dst = &l0[node][0];
        } else if (tid < 160) {              // lut1: 4 nodes * 8 pairs
            int t = tid - 128;
            int node = t >> 3; k = t & 7;
            src = lut1 + (c * 4 + node) * 16;
            dst = &l1[node][0];
        } else {                             // lut2: 1 node * 8 pairs
            int t = tid - 160; k = t & 7;
            src = lut2 + c * 16;
            dst = l2;
        }
        float a = src[2 * k], b = src[2 * k + 1];
        float ea = 1.0f / (1.0f + __expf(-a));
        float eb = 1.0f / (1.0f + __expf(-b));
        dst[k]     = ea;
        dst[k + 8] = eb - ea;
    }

    // ---- two patches per thread; 49 * 512 == 25088, no tail ----
    const int pA = blockIdx.x * (TP * THREADS) + tid;
    const int pB = pA + THREADS;

    const int bA = pA / PPI, qA = pA - bA * PPI;
    const int iA = qA / WPOUT, jA = qA - iA * WPOUT;
    const int bB = pB / PPI, qB = pB - bB * PPI;
    const int iB = qB / WPOUT, jB = qB - iB * WPOUT;

    const float* xA = x + bA * 1024 + iA * 32 + jA;
    const float* xB = x + bB * 1024 + iB * 32 + jB;

    f32x32 pvA, pvB;                       // movrel-gatherable register vectors
#pragma unroll
    for (int di = 0; di < KK; ++di) {
#pragma unroll
        for (int dj = 0; dj < KK; ++dj) {
            const int o = di * 5 + dj, go = di * 32 + dj;
            pvA[o] = xA[go];
            pvB[o] = xB[go];
        }
    }

    __syncthreads();   // LUTs ready

    // ---- layer 0: 16 nodes; uniform-index movrel gathers (shared m0 across both vectors) ----
    const int* id0 = idx0 + c * 64;        // block-uniform -> scalar loads
    f32x16 hA, hB;
#pragma unroll
    for (int m = 0; m < 16; ++m) {
        const int i0 = __builtin_amdgcn_readfirstlane(id0[m * 4 + 0]);
        const int i1 = __builtin_amdgcn_readfirstlane(id0[m * 4 + 1]);
        const int i2 = __builtin_amdgcn_readfirstlane(id0[m * 4 + 2]);
        const int i3 = __builtin_amdgcn_readfirstlane(id0[m * 4 + 3]);
        const v2f s0 = { pvA[i0], pvB[i0] };
        const v2f s1 = { pvA[i1], pvB[i1] };
        const v2f s2 = { pvA[i2], pvB[i2] };
        const v2f s3 = { pvA[i3], pvB[i3] };
        const v2f r = node2(&l0[m][0], s0, s1, s2, s3);
        hA[m] = r.x;
        hB[m] = r.y;
    }

    // ---- layer 1: 4 nodes; uniform-index movrel gathers from hA/hB ----
    const int* id1 = idx1 + c * 16;
    v2f h1[4];                              // static-indexed only
#pragma unroll
    for (int m = 0; m < 4; ++m) {
        const int i0 = __builtin_amdgcn_readfirstlane(id1[m * 4 + 0]);
        const int i1 = __builtin_amdgcn_readfirstlane(id1[m * 4 + 1]);
        const int i2 = __builtin_amdgcn_readfirstlane(id1[m * 4 + 2]);
        const int i3 = __builtin_amdgcn_readfirstlane(id1[m * 4 + 3]);
        const v2f s0 = { hA[i0], hB[i0] };
        const v2f s1 = { hA[i1], hB[i1] };
        const v2f s2 = { hA[i2], hB[i2] };
        const v2f s3 = { hA[i3], hB[i3] };
        h1[m] = node2(&l1[m][0], s0, s1, s2, s3);
    }

    // ---- layer 2: 1 node; 4-way uniform select from h1 (constant indices after unroll) ----
    const int* id2 = idx2 + c * 4;
    v2f s[4];
#pragma unroll
    for (int jj = 0; jj < 4; ++jj) {
        const int ii = __builtin_amdgcn_readfirstlane(id2[jj]);
        s[jj] = (ii == 0) ? h1[0] : (ii == 1) ? h1[1] : (ii == 2) ? h1[2] : h1[3];
    }
    const v2f r = node2(l2, s[0], s[1], s[2], s[3]);

    out[(bA * NCH + c) * PPI + qA] = r.x;
    out[(bB * NCH + c) * PPI + qB] = r.y;
}

extern "C" void kernel_launch(void* const* d_in, const int* in_sizes, int n_in,
                              void* d_out, int out_size, void* d_ws, size_t ws_size,
                              hipStream_t stream) {
    const float* x    = (const float*)d_in[0];
    const float* lut0 = (const float*)d_in[1];
    const float* lut1 = (const float*)d_in[2];
    const float* lut2 = (const float*)d_in[3];
    const int*   idx0 = (const int*)d_in[4];
    const int*   idx1 = (const int*)d_in[5];
    const int*   idx2 = (const int*)d_in[6];
    float* out = (float*)d_out;

    dim3 grid(NPATCH / (TP * THREADS), NCH);   // 49 x 64
    dim3 block(THREADS);
    dwn_conv_lut_kernel<<<grid, block, 0, stream>>>(x, lut0, lut1, lut2,
                                                    idx0, idx1, idx2, out);
}